// Round 15
// baseline (115.523 us; speedup 1.0000x reference)
//
#include <hip/hip_runtime.h>
#include <stdint.h>

// Problem constants (fixed by reference)
#define N_IMG   16
#define C_IN    256
#define H_IN    32
#define W_IN    32
#define OH      30
#define OW      30
#define K_SEL   1152                   // C*KH*KW/2
#define OUTC    512
#define RY_TOT  (N_IMG * OH)           // 480 (n,y) rows
#define M_HAT   (RY_TOT * 32)          // 15360 = padded M (ow 30 -> 32)
#define X_ELEMS (N_IMG * C_IN * H_IN * W_IN)   // 4194304
#define OUT_SP  (OH * OW)              // 900
#define CHW     (C_IN * H_IN * W_IN)   // 262144

#define TO      128                    // o-tile
#define TM      64                     // m-tile = 2 ry rows x 32 xw
#define NMT     (M_HAT / TM)           // 240
#define NOT     (OUTC / TO)            // 4
#define BSTR    40                     // (fallback) Bs row stride
#define KITER   (K_SEL / 32)           // 36

#define NPACK   (NMT * KITER)          // 8640 B-pack blocks
#define NPREPW  (36 * 16)              // 576 w-transpose blocks
#define WTF_BYTES 1179648u
#define BF_BYTES  35389440u            // 15360*1152*2

typedef float f32x4  __attribute__((ext_vector_type(4)));
typedef short bf16x8 __attribute__((ext_vector_type(8)));   // 8 bf16 = 4 VGPRs

__device__ __forceinline__ unsigned short f2bf(float f) {   // fp32 -> bf16 RNE
    unsigned int u = __float_as_uint(f);
    u += 0x7FFFu + ((u >> 16) & 1u);
    return (unsigned short)(u >> 16);
}

// async global->LDS, 16B/lane (fallback path only).
__device__ __forceinline__ void gl_lds16(const void* g, void* lds) {
    __builtin_amdgcn_global_load_lds(
        (const __attribute__((address_space(1))) unsigned int*)g,
        (__attribute__((address_space(3))) unsigned int*)lds,
        16, 0, 0);
}

// ===========================================================================
// R15. R14 decode: the ~44.5us 256MiB fill in dur_us is the harness ws
// re-poison => ws_size = 256MiB => PATH A ran; prepA+gemmA ~= 59us ~=
// prepB+gemmB. gemmA still pays a barrier+2 counted waits per step for
// ~400cy of wave work. Since BOTH operands are fragment-ordered in global
// memory, LDS staging buys nothing: gemmC loads A (2 dwordx4) and B
// (4 dwordx4, 1KB contiguous per fragment per wave) STRAIGHT from global.
// Zero LDS, zero in-loop barriers, zero waitcnt asm; register double-buffer
// (literal indices via unroll-2); waves free-run. Cost: Bf read 4x per
// block (per wave) from L2 (~16us L2 service, well under BW).
// ===========================================================================

// ---------------------------------------------------------------------------
// prepA (R14-verified, byte-identical): blocks [0,8640) pack B tiles into
// fragment order Bf[(mt*36+kt)*2048 + t*8]; blocks [8640,9216) transpose w
// into wTf fragment order.
// ---------------------------------------------------------------------------
__global__ void prepA_kernel(const int* __restrict__ idx, const float* __restrict__ w,
                             const float* __restrict__ x,
                             unsigned short* __restrict__ wTf,
                             unsigned short* __restrict__ Bf) {
    __shared__ float tile[32][33];
    const int bid = blockIdx.x, t = threadIdx.x;

    if (bid < NPACK) {
        const int mt = bid / KITER, kt = bid - mt * KITER;
        const int lane = t & 63, ns = t >> 6;
        const int quad = lane >> 4, lo = lane & 15;
        const int m  = ns * 16 + lo;
        const int ry = m >> 5, xw = m & 31;
        const int ryg = mt * 2 + ry;
        const int n = ryg / 30, y = ryg - n * 30;
        const int base = n * CHW + y * W_IN + min(xw, 29);   // clamp: in-bounds
        unsigned int uu[4];
#pragma unroll
        for (int jp = 0; jp < 4; ++jp) {
            unsigned short ua, ub;
            {
                int k = kt * 32 + quad * 8 + jp * 2;
                int v = idx[k];
                int c = v / 9, rem = v - c * 9;
                int i = rem / 3, j2 = rem - i * 3;
                ua = f2bf(x[base + c * (H_IN * W_IN) + i * W_IN + j2]);
            }
            {
                int k = kt * 32 + quad * 8 + jp * 2 + 1;
                int v = idx[k];
                int c = v / 9, rem = v - c * 9;
                int i = rem / 3, j2 = rem - i * 3;
                ub = f2bf(x[base + c * (H_IN * W_IN) + i * W_IN + j2]);
            }
            uu[jp] = (unsigned int)ua | ((unsigned int)ub << 16);
        }
        uint4 pk; pk.x = uu[0]; pk.y = uu[1]; pk.z = uu[2]; pk.w = uu[3];
        *reinterpret_cast<uint4*>(&Bf[(size_t)bid * 2048 + t * 8]) = pk;
    } else {
        const int b = bid - NPACK;
        const int bx = b % 36, by = b / 36;
        const int s0 = bx * 32, o0 = by * 32;
        const int oc = t & 31, sg = t >> 5;
#pragma unroll
        for (int i = 0; i < 4; ++i) {
            int sl = sg * 4 + i;
            tile[sl][oc] = w[(s0 + sl) * OUTC + o0 + oc];
        }
        __syncthreads();
        const int ol = t >> 3, sq = t & 7;
        unsigned int u0 = (unsigned int)f2bf(tile[sq * 4 + 0][ol]) |
                          ((unsigned int)f2bf(tile[sq * 4 + 1][ol]) << 16);
        unsigned int u1 = (unsigned int)f2bf(tile[sq * 4 + 2][ol]) |
                          ((unsigned int)f2bf(tile[sq * 4 + 3][ol]) << 16);
        uint2 pk; pk.x = u0; pk.y = u1;
        const size_t fi =
            (((((size_t)(by >> 1) * KITER + bx) * 4 + ((by * 2 + (ol >> 4)) & 3)) * 64
              + (sq >> 1) * 16 + (ol & 15)) * 8) + (sq & 1) * 4;
        *reinterpret_cast<uint2*>(&wTf[fi]) = pk;
    }
}

// ---------------------------------------------------------------------------
// gemmC: pure global->register->MFMA. Per step per wave: 2 A dwordx4 +
// 4 B dwordx4 (all coalesced; B fragment = 1KB contiguous per wave) +
// 8 MFMA. No LDS, no barriers, no inline asm: compiler inserts counted
// vmcnt from register deps; named double buffers with literal indices
// (p/q fold to constants under unroll 2). ~90 VGPR -> no spill risk.
// ---------------------------------------------------------------------------
__global__ __launch_bounds__(256, 4)
void gemmC_kernel(const unsigned short* __restrict__ wTf,
                  const unsigned short* __restrict__ Bf,
                  float* __restrict__ out) {
    const int t    = threadIdx.x;
    const int wave = t >> 6;
    const int lane = t & 63;
    const int quad = lane >> 4;
    const int lo   = lane & 15;

    const int bid = blockIdx.x;
    const int mt  = bid % NMT;
    const int ot  = bid / NMT;                     // ot-siblings 240 apart -> same XCD
    const int oBase = ot * TO;
    const int mBase = mt * TM;

    // A fragment base (R12-verified mapping)
    const int ow64 = ot * 2 + (wave >> 1);
    const int idx0 = (wave * 2) & 3;
    const unsigned short* aP =
        wTf + ((size_t)ow64 * KITER * 4 + idx0) * 512 + (size_t)lane * 8;
    // B tile base: fragment ns of tile (mt,kt) at + kt*2048 + ns*512 + lane*8
    const unsigned short* bP =
        Bf + (size_t)mt * KITER * 2048 + (size_t)lane * 8;

    f32x4 acc[2][4] = {};
    bf16x8 aR[2][2], bR[2][4];                     // [buf][frag], literal-indexed

    // ---- prologue: tile 0 into buffer 0 ----
    aR[0][0] = *(const bf16x8*)(aP);
    aR[0][1] = *(const bf16x8*)(aP + 512);
#pragma unroll
    for (int ns = 0; ns < 4; ++ns)
        bR[0][ns] = *(const bf16x8*)(bP + ns * 512);

    // ---- main loop: free-running, reg double-buffer, no sync ----
#pragma unroll 2
    for (int kt = 0; kt < KITER; ++kt) {
        const int p = kt & 1, q = p ^ 1;
        const int k1 = (kt + 1 < KITER ? kt + 1 : KITER - 1);

        // issue next tile's 6 loads into buffer q
        aR[q][0] = *(const bf16x8*)(aP + (size_t)(k1 * 4) * 512);
        aR[q][1] = *(const bf16x8*)(aP + (size_t)(k1 * 4 + 1) * 512);
#pragma unroll
        for (int ns = 0; ns < 4; ++ns)
            bR[q][ns] = *(const bf16x8*)(bP + (size_t)k1 * 2048 + ns * 512);

        // compute tile kt from buffer p (compiler waits only on buf p regs)
#pragma unroll
        for (int ms = 0; ms < 2; ++ms)
#pragma unroll
            for (int ns = 0; ns < 4; ++ns)
                acc[ms][ns] = __builtin_amdgcn_mfma_f32_16x16x32_bf16(
                    aR[p][ms], bR[p][ns], acc[ms][ns], 0, 0, 0);
    }

    // Epilogue (R12-verified): D row = o (quad*4+r), col = m (lane&15).
#pragma unroll
    for (int ns = 0; ns < 4; ++ns) {
        const int mh  = mBase + ns * 16 + lo;
        const int xwe = mh & 31;
        const int ryg = mh >> 5;
        const int n = ryg / 30, y = ryg - n * 30;
        if (xwe < OW) {
            const size_t ob = (size_t)n * (OUTC * OUT_SP) + (size_t)y * OW + xwe;
#pragma unroll
            for (int ms = 0; ms < 2; ++ms) {
                const int o0 = oBase + wave * 32 + ms * 16 + quad * 4;
#pragma unroll
                for (int r = 0; r < 4; ++r)
                    out[ob + (size_t)(o0 + r) * OUT_SP] = acc[ms][ns][r];
            }
        }
    }
}

// ===========================================================================
// PATH B (fallback, ws too small): R12 kernels verbatim (measured 104us).
// ===========================================================================
__global__ void prepB_kernel(const int* __restrict__ idx, const float* __restrict__ w,
                             int* __restrict__ koff, unsigned short* __restrict__ wTf) {
    __shared__ float tile[32][33];
    const int bx = blockIdx.x, by = blockIdx.y, t = threadIdx.x;
    if (by == 0) {
        int k = bx * 256 + t;
        if (k < K_SEL) {
            int v = idx[k];
            int c = v / 9, rem = v - c * 9;
            int i = rem / 3, j = rem - i * 3;
            koff[k] = c * (H_IN * W_IN) + i * W_IN + j;
        }
    }
    const int s0 = bx * 32, o0 = by * 32;
    const int oc = t & 31, sg = t >> 5;
#pragma unroll
    for (int i = 0; i < 4; ++i) {
        int sl = sg * 4 + i;
        tile[sl][oc] = w[(s0 + sl) * OUTC + o0 + oc];
    }
    __syncthreads();
    const int ol = t >> 3, sq = t & 7;
    unsigned int u0 = (unsigned int)f2bf(tile[sq * 4 + 0][ol]) |
                      ((unsigned int)f2bf(tile[sq * 4 + 1][ol]) << 16);
    unsigned int u1 = (unsigned int)f2bf(tile[sq * 4 + 2][ol]) |
                      ((unsigned int)f2bf(tile[sq * 4 + 3][ol]) << 16);
    uint2 pk; pk.x = u0; pk.y = u1;
    const size_t fi =
        (((((size_t)(by >> 1) * KITER + bx) * 4 + ((by * 2 + (ol >> 4)) & 3)) * 64
          + (sq >> 1) * 16 + (ol & 15)) * 8) + (sq & 1) * 4;
    *reinterpret_cast<uint2*>(&wTf[fi]) = pk;
}

__global__ __launch_bounds__(256, 4)
void gemmB_kernel(const unsigned short* __restrict__ wTf, const float* __restrict__ x,
                  const int* __restrict__ koff, float* __restrict__ out) {
    __shared__ __align__(16) unsigned short Bs[2][TM * BSTR];
    __shared__ int koS[K_SEL];
    const int t = threadIdx.x, wave = t >> 6, lane = t & 63;
    const int quad = lane >> 4, lo = lane & 15;
    const int bid = blockIdx.x, mt = bid % NMT, ot = bid / NMT;
    const int oBase = ot * TO, mBase = mt * TM;
    for (int i = t; i < K_SEL; i += 256) koS[i] = koff[i];
    const int xw = t & 31, xwc = min(xw, 29);
    int basex[2];
#pragma unroll
    for (int ry = 0; ry < 2; ++ry) {
        int ryg = mt * 2 + ry;
        int n = ryg / 30, y = ryg - n * 30;
        basex[ry] = n * CHW + y * W_IN + xwc;
    }
    const int kq4 = t >> 5, ks = kq4 * 4;
    const int ow64 = ot * 2 + (wave >> 1);
    const int idx0 = (wave * 2) & 3;
    const unsigned short* aP =
        wTf + ((size_t)ow64 * KITER * 4 + idx0) * 512 + (size_t)lane * 8;
    const unsigned short* bB[2] = {
        &Bs[0][lo * BSTR + quad * 8], &Bs[1][lo * BSTR + quad * 8] };
    unsigned short* bW[2] = {
        &Bs[0][xw * BSTR + ks], &Bs[1][xw * BSTR + ks] };
    __syncthreads();
    f32x4 acc[2][4] = {};
    bf16x8 aR[2][2];
    float v[2][2][4];
    {
        int4 k4 = *(const int4*)&koS[ks];
#pragma unroll
        for (int ry = 0; ry < 2; ++ry)
#pragma unroll
            for (int j = 0; j < 4; ++j)
                v[0][ry][j] = x[basex[ry] + ((const int*)&k4)[j]];
    }
    asm volatile("s_waitcnt vmcnt(0)" ::: "memory");
#pragma unroll
    for (int ry = 0; ry < 2; ++ry) {
        unsigned int u0 = (unsigned int)f2bf(v[0][ry][0]) |
                          ((unsigned int)f2bf(v[0][ry][1]) << 16);
        unsigned int u1 = (unsigned int)f2bf(v[0][ry][2]) |
                          ((unsigned int)f2bf(v[0][ry][3]) << 16);
        uint2 pk; pk.x = u0; pk.y = u1;
        *reinterpret_cast<uint2*>(bW[0] + ry * 32 * BSTR) = pk;
    }
#pragma unroll
    for (int ms = 0; ms < 2; ++ms)
        aR[0][ms] = *(const bf16x8*)(aP + (size_t)ms * 512);
    {
        int4 k4 = *(const int4*)&koS[32 + ks];
#pragma unroll
        for (int ry = 0; ry < 2; ++ry)
#pragma unroll
            for (int j = 0; j < 4; ++j)
                v[1][ry][j] = x[basex[ry] + ((const int*)&k4)[j]];
    }
    asm volatile("s_waitcnt lgkmcnt(0)" ::: "memory");
    __builtin_amdgcn_s_barrier();
#pragma unroll 2
    for (int kt = 0; kt < KITER; ++kt) {
        const int p = kt & 1, q = p ^ 1;
        bf16x8 b[4];
#pragma unroll
        for (int ns = 0; ns < 4; ++ns)
            b[ns] = *(const bf16x8*)(bB[p] + ns * 16 * BSTR);
        {
            const int k1 = (kt + 1 < KITER ? kt + 1 : KITER - 1);
#pragma unroll
            for (int ms = 0; ms < 2; ++ms)
                aR[q][ms] = *(const bf16x8*)(aP + (size_t)(k1 * 4 + ms) * 512);
        }
        {
            const int k2 = (kt + 2 < KITER ? kt + 2 : KITER - 1) * 32;
            int4 k4 = *(const int4*)&koS[k2 + ks];
#pragma unroll
            for (int ry = 0; ry < 2; ++ry)
#pragma unroll
                for (int j = 0; j < 4; ++j)
                    v[p][ry][j] = x[basex[ry] + ((const int*)&k4)[j]];
        }
        asm volatile("s_waitcnt vmcnt(10)" ::: "memory");
        asm volatile("s_waitcnt lgkmcnt(0)" ::: "memory");
        __builtin_amdgcn_sched_barrier(0);
#pragma unroll
        for (int ry = 0; ry < 2; ++ry) {
            unsigned int u0 = (unsigned int)f2bf(v[q][ry][0]) |
                              ((unsigned int)f2bf(v[q][ry][1]) << 16);
            unsigned int u1 = (unsigned int)f2bf(v[q][ry][2]) |
                              ((unsigned int)f2bf(v[q][ry][3]) << 16);
            uint2 pk; pk.x = u0; pk.y = u1;
            *reinterpret_cast<uint2*>(bW[q] + ry * 32 * BSTR) = pk;
        }
#pragma unroll
        for (int ms = 0; ms < 2; ++ms)
#pragma unroll
            for (int ns = 0; ns < 4; ++ns)
                acc[ms][ns] = __builtin_amdgcn_mfma_f32_16x16x32_bf16(
                    aR[p][ms], b[ns], acc[ms][ns], 0, 0, 0);
        asm volatile("s_waitcnt lgkmcnt(0)" ::: "memory");
        __builtin_amdgcn_s_barrier();
    }
#pragma unroll
    for (int ns = 0; ns < 4; ++ns) {
        const int mh  = mBase + ns * 16 + lo;
        const int xwe = mh & 31;
        const int ryg = mh >> 5;
        const int n = ryg / 30, y = ryg - n * 30;
        if (xwe < OW) {
            const size_t ob = (size_t)n * (OUTC * OUT_SP) + (size_t)y * OW + xwe;
#pragma unroll
            for (int ms = 0; ms < 2; ++ms) {
                const int o0 = oBase + wave * 32 + ms * 16 + quad * 4;
#pragma unroll
                for (int r = 0; r < 4; ++r)
                    out[ob + (size_t)(o0 + r) * OUT_SP] = acc[ms][ns][r];
            }
        }
    }
}

// ---------------------------------------------------------------------------
extern "C" void kernel_launch(void* const* d_in, const int* in_sizes, int n_in,
                              void* d_out, int out_size, void* d_ws, size_t ws_size,
                              hipStream_t stream) {
    const float* x   = (const float*)d_in[0];
    const float* w   = (const float*)d_in[1];
    const int*   idx = (const int*)d_in[2];
    float*       out = (float*)d_out;
    char* ws = (char*)d_ws;

    if (ws_size >= (size_t)WTF_BYTES + BF_BYTES) {
        // PATH A: ws = wTf 1.18MB | Bf 35.4MB (fragment-packed im2col)
        unsigned short* wTf = (unsigned short*)ws;
        unsigned short* Bf  = (unsigned short*)(ws + WTF_BYTES);
        prepA_kernel<<<dim3(NPACK + NPREPW), dim3(256), 0, stream>>>(
            idx, w, x, wTf, Bf);
        gemmC_kernel<<<dim3(NMT * NOT), dim3(256), 0, stream>>>(wTf, Bf, out);
    } else {
        // PATH B (R12 fallback): ws = koff 4608B | wTf 1.18MB
        int*            koff = (int*)ws;
        unsigned short* wTf  = (unsigned short*)(ws + 4608);
        prepB_kernel<<<dim3(K_SEL / 32, OUTC / 32), dim3(256), 0, stream>>>(
            idx, w, koff, wTf);
        gemmB_kernel<<<dim3(NMT * NOT), dim3(256), 0, stream>>>(wTf, x, koff, out);
    }
}

// Round 16
// 102.596 us; speedup vs baseline: 1.1260x; 1.1260x over previous
//
#include <hip/hip_runtime.h>
#include <stdint.h>

// Problem constants (fixed by reference)
#define N_IMG   16
#define C_IN    256
#define H_IN    32
#define W_IN    32
#define OH      30
#define OW      30
#define K_SEL   1152                   // C*KH*KW/2
#define OUTC    512
#define RY_TOT  (N_IMG * OH)           // 480 (n,y) rows
#define M_HAT   (RY_TOT * 32)          // 15360 = padded M (ow 30 -> 32)
#define X_ELEMS (N_IMG * C_IN * H_IN * W_IN)   // 4194304
#define OUT_SP  (OH * OW)              // 900
#define CHW     (C_IN * H_IN * W_IN)   // 262144

#define TO      128                    // o-tile
#define TM      64                     // m-tile = 2 ry rows x 32 xw
#define NMT     (M_HAT / TM)           // 240
#define NOT     (OUTC / TO)            // 4
#define BSTR    40                     // (fallback) Bs row stride
#define KITER   (K_SEL / 32)           // 36

#define NPACK   (NMT * KITER)          // 8640 B-pack blocks
#define NPREPW  (36 * 16)              // 576 w-transpose blocks
#define WTF_BYTES 1179648u
#define BF_BYTES  35389440u            // 15360*1152*2

typedef float f32x4  __attribute__((ext_vector_type(4)));
typedef short bf16x8 __attribute__((ext_vector_type(8)));   // 8 bf16 = 4 VGPRs

__device__ __forceinline__ unsigned short f2bf(float f) {   // fp32 -> bf16 RNE
    unsigned int u = __float_as_uint(f);
    u += 0x7FFFu + ((u >> 16) & 1u);
    return (unsigned short)(u >> 16);
}

// async global->LDS, 16B/lane; LDS dst wave-uniform base, HW adds lane*16.
__device__ __forceinline__ void gl_lds16(const void* g, void* lds) {
    __builtin_amdgcn_global_load_lds(
        (const __attribute__((address_space(1))) unsigned int*)g,
        (__attribute__((address_space(3))) unsigned int*)lds,
        16, 0, 0);
}

// ===========================================================================
// R16. R15's +12us regression == the added 414MB of L2 B-traffic at L2 BW:
// gemm is L2-traffic/latency bound and the LDS broadcast of B is essential.
// Base = R14 (best, 103.7). Two conservative fixes:
//  (a) gemmA-v2: Bf staged TWO steps ahead into a 4-deep Bs ring. The one
//      per-step vmcnt(3) (needed for A(kt) anyway) also drains the gl_lds
//      issued a full step earlier -> the barrier carries NO memory wait.
//  (b) prepA-v2: idx->koff decoded once per block (32 thr + barrier) into
//      koS2 instead of per-thread x8 integer-div chains (~140 VALU saved).
// Everything else byte-identical to R14.
// ===========================================================================

// ---------------------------------------------------------------------------
// prepA-v2: blocks [0,8640) pack B tile (mt,kt) -> Bf[(mt*36+kt)*2048+t*8],
// thread t = ns*64+lane owns m=ns*16+(lane&15), k=kt*32+(lane>>4)*8+j
// (fragment convention verified R11-R14). koff via per-block koS2.
// Blocks [8640,9216) transpose w into wTf (R12-verified body).
// ---------------------------------------------------------------------------
__global__ void prepA_kernel(const int* __restrict__ idx, const float* __restrict__ w,
                             const float* __restrict__ x,
                             unsigned short* __restrict__ wTf,
                             unsigned short* __restrict__ Bf) {
    __shared__ float tile[32][33];
    __shared__ int koS2[32];
    const int bid = blockIdx.x, t = threadIdx.x;

    if (bid < NPACK) {
        const int mt = bid / KITER, kt = bid - mt * KITER;
        if (t < 32) {                              // decode once per block
            int v = idx[kt * 32 + t];
            int c = v / 9, rem = v - c * 9;
            int i = rem / 3, j = rem - i * 3;
            koS2[t] = c * (H_IN * W_IN) + i * W_IN + j;
        }
        __syncthreads();
        const int lane = t & 63, ns = t >> 6;
        const int quad = lane >> 4, lo = lane & 15;
        const int m  = ns * 16 + lo;
        const int ry = m >> 5, xw = m & 31;
        const int ryg = mt * 2 + ry;
        const int n = ryg / 30, y = ryg - n * 30;
        const int base = n * CHW + y * W_IN + min(xw, 29);   // clamp: in-bounds
        unsigned int uu[4];
#pragma unroll
        for (int jp = 0; jp < 4; ++jp) {
            const int k0 = quad * 8 + jp * 2;
            unsigned short ua = f2bf(x[base + koS2[k0]]);
            unsigned short ub = f2bf(x[base + koS2[k0 + 1]]);
            uu[jp] = (unsigned int)ua | ((unsigned int)ub << 16);
        }
        uint4 pk; pk.x = uu[0]; pk.y = uu[1]; pk.z = uu[2]; pk.w = uu[3];
        *reinterpret_cast<uint4*>(&Bf[(size_t)bid * 2048 + t * 8]) = pk;
    } else {
        const int b = bid - NPACK;
        const int bx = b % 36, by = b / 36;
        const int s0 = bx * 32, o0 = by * 32;
        const int oc = t & 31, sg = t >> 5;
#pragma unroll
        for (int i = 0; i < 4; ++i) {
            int sl = sg * 4 + i;
            tile[sl][oc] = w[(s0 + sl) * OUTC + o0 + oc];
        }
        __syncthreads();
        const int ol = t >> 3, sq = t & 7;
        unsigned int u0 = (unsigned int)f2bf(tile[sq * 4 + 0][ol]) |
                          ((unsigned int)f2bf(tile[sq * 4 + 1][ol]) << 16);
        unsigned int u1 = (unsigned int)f2bf(tile[sq * 4 + 2][ol]) |
                          ((unsigned int)f2bf(tile[sq * 4 + 3][ol]) << 16);
        uint2 pk; pk.x = u0; pk.y = u1;
        const size_t fi =
            (((((size_t)(by >> 1) * KITER + bx) * 4 + ((by * 2 + (ol >> 4)) & 3)) * 64
              + (sq >> 1) * 16 + (ol & 15)) * 8) + (sq & 1) * 4;
        *reinterpret_cast<uint2*>(&wTf[fi]) = pk;
    }
}

// ---------------------------------------------------------------------------
// gemmA-v2: per step per wave: 1 gl_lds16 (tile kt+2), 2 A dwordx4 (kt+1),
// 4 ds_read_b128 (tile kt), 8 MFMA. Bs 4-deep ring (16KB).
// Ledger (per wave, issue order per step: [gl(kt+2), A(kt+1)x2]):
//   top of kt: outstanding = A(kt)x2 [@kt-1] + gl(kt+1) [@kt-1, already
//   drained @kt-1's vmcnt... see below]. After this step's 3 issues:
//   A(kt)x2, gl(kt+2), A(kt+1)x2 (+ gl(kt+1) if not yet complete) ->
//   vmcnt(3) keeps {gl(kt+2), A(kt+1)x2}; drains A(kt) (MFMA operands)
//   AND gl(kt+1) (issued a FULL STEP earlier -> usually already done ->
//   no stall). Barrier then carries no memory wait: gl(kt+1) visible for
//   everyone's read @kt+1.
// Ring hazards: write@kt targets (kt+2)&3, last read @kt-2, >=2 barriers
//   between read and rewrite; RAW write@kt -> read@kt+2 crosses barriers
//   @kt,@kt+1. Prologue: gl(0),gl(1),A(0)x2; vmcnt(2) drains both gl;
//   barrier. Tail: clamped dup stages into rings whose readers are done.
// ---------------------------------------------------------------------------
__global__ __launch_bounds__(256, 4)
void gemmA_kernel(const unsigned short* __restrict__ wTf,
                  const unsigned short* __restrict__ Bf,
                  float* __restrict__ out) {
    __shared__ __align__(16) unsigned short Bs[4][2048];   // 4 x 4KB ring

    const int t    = threadIdx.x;
    const int wave = t >> 6;
    const int lane = t & 63;
    const int quad = lane >> 4;
    const int lo   = lane & 15;

    const int bid = blockIdx.x;
    const int mt  = bid % NMT;
    const int ot  = bid / NMT;                     // ot-siblings 240 apart -> same XCD
    const int oBase = ot * TO;
    const int mBase = mt * TM;

    // A fragment base (R12-verified mapping)
    const int ow64 = ot * 2 + (wave >> 1);
    const int idx0 = (wave * 2) & 3;
    const unsigned short* aP =
        wTf + ((size_t)ow64 * KITER * 4 + idx0) * 512 + (size_t)lane * 8;
    // B tile base for this (mt, wave-quarter)
    const unsigned short* bfP =
        Bf + (size_t)mt * KITER * 2048 + wave * 512 + (size_t)lane * 8;

    unsigned short* ldst[4] = {
        &Bs[0][wave * 512], &Bs[1][wave * 512],
        &Bs[2][wave * 512], &Bs[3][wave * 512] };
    const unsigned short* bRd[4] = {
        &Bs[0][lane * 8], &Bs[1][lane * 8],
        &Bs[2][lane * 8], &Bs[3][lane * 8] };

    f32x4 acc[2][4] = {};
    bf16x8 aR[2][2];

    // ---- prologue: stage tiles 0,1; A(0); drain both gl; barrier ----
    gl_lds16(bfP, ldst[0]);
    gl_lds16(bfP + 2048, ldst[1]);
    aR[0][0] = *(const bf16x8*)(aP);
    aR[0][1] = *(const bf16x8*)(aP + 512);
    asm volatile("s_waitcnt vmcnt(2)" ::: "memory");   // gl(0), gl(1) done
    __builtin_amdgcn_s_barrier();                      // Bs[0], Bs[1] visible

    // ---- main loop: one stall-free barrier per step ----
#pragma unroll 4
    for (int kt = 0; kt < KITER; ++kt) {
        const int p = kt & 1, q = p ^ 1;
        const int c = kt & 3;
        const int k1 = (kt + 1 < KITER ? kt + 1 : KITER - 1);
        const int k2 = (kt + 2 < KITER ? kt + 2 : KITER - 1);

        gl_lds16(bfP + (size_t)k2 * 2048, ldst[(kt + 2) & 3]);
        aR[q][0] = *(const bf16x8*)(aP + (size_t)(k1 * 4) * 512);
        aR[q][1] = *(const bf16x8*)(aP + (size_t)(k1 * 4 + 1) * 512);

        bf16x8 b[4];
#pragma unroll
        for (int ns = 0; ns < 4; ++ns)
            b[ns] = *(const bf16x8*)(bRd[c] + ns * 512);
        asm volatile("s_waitcnt lgkmcnt(0)" ::: "memory");  // b frags in regs
        __builtin_amdgcn_sched_barrier(0);                  // rule #18 fence
        asm volatile("s_waitcnt vmcnt(3)" ::: "memory");    // A(kt) + gl(kt+1)

#pragma unroll
        for (int ms = 0; ms < 2; ++ms)
#pragma unroll
            for (int ns = 0; ns < 4; ++ns)
                acc[ms][ns] = __builtin_amdgcn_mfma_f32_16x16x32_bf16(
                    aR[p][ms], b[ns], acc[ms][ns], 0, 0, 0);

        __builtin_amdgcn_s_barrier();                  // no memory wait attached
    }

    // Epilogue (R12-verified): D row = o (quad*4+r), col = m (lane&15).
#pragma unroll
    for (int ns = 0; ns < 4; ++ns) {
        const int mh  = mBase + ns * 16 + lo;
        const int xwe = mh & 31;
        const int ryg = mh >> 5;
        const int n = ryg / 30, y = ryg - n * 30;
        if (xwe < OW) {
            const size_t ob = (size_t)n * (OUTC * OUT_SP) + (size_t)y * OW + xwe;
#pragma unroll
            for (int ms = 0; ms < 2; ++ms) {
                const int o0 = oBase + wave * 32 + ms * 16 + quad * 4;
#pragma unroll
                for (int r = 0; r < 4; ++r)
                    out[ob + (size_t)(o0 + r) * OUT_SP] = acc[ms][ns][r];
            }
        }
    }
}

// ===========================================================================
// PATH B (fallback, ws too small): R12 kernels verbatim (measured 104us).
// ===========================================================================
__global__ void prepB_kernel(const int* __restrict__ idx, const float* __restrict__ w,
                             int* __restrict__ koff, unsigned short* __restrict__ wTf) {
    __shared__ float tile[32][33];
    const int bx = blockIdx.x, by = blockIdx.y, t = threadIdx.x;
    if (by == 0) {
        int k = bx * 256 + t;
        if (k < K_SEL) {
            int v = idx[k];
            int c = v / 9, rem = v - c * 9;
            int i = rem / 3, j = rem - i * 3;
            koff[k] = c * (H_IN * W_IN) + i * W_IN + j;
        }
    }
    const int s0 = bx * 32, o0 = by * 32;
    const int oc = t & 31, sg = t >> 5;
#pragma unroll
    for (int i = 0; i < 4; ++i) {
        int sl = sg * 4 + i;
        tile[sl][oc] = w[(s0 + sl) * OUTC + o0 + oc];
    }
    __syncthreads();
    const int ol = t >> 3, sq = t & 7;
    unsigned int u0 = (unsigned int)f2bf(tile[sq * 4 + 0][ol]) |
                      ((unsigned int)f2bf(tile[sq * 4 + 1][ol]) << 16);
    unsigned int u1 = (unsigned int)f2bf(tile[sq * 4 + 2][ol]) |
                      ((unsigned int)f2bf(tile[sq * 4 + 3][ol]) << 16);
    uint2 pk; pk.x = u0; pk.y = u1;
    const size_t fi =
        (((((size_t)(by >> 1) * KITER + bx) * 4 + ((by * 2 + (ol >> 4)) & 3)) * 64
          + (sq >> 1) * 16 + (ol & 15)) * 8) + (sq & 1) * 4;
    *reinterpret_cast<uint2*>(&wTf[fi]) = pk;
}

__global__ __launch_bounds__(256, 4)
void gemmB_kernel(const unsigned short* __restrict__ wTf, const float* __restrict__ x,
                  const int* __restrict__ koff, float* __restrict__ out) {
    __shared__ __align__(16) unsigned short Bs[2][TM * BSTR];
    __shared__ int koS[K_SEL];
    const int t = threadIdx.x, wave = t >> 6, lane = t & 63;
    const int quad = lane >> 4, lo = lane & 15;
    const int bid = blockIdx.x, mt = bid % NMT, ot = bid / NMT;
    const int oBase = ot * TO, mBase = mt * TM;
    for (int i = t; i < K_SEL; i += 256) koS[i] = koff[i];
    const int xw = t & 31, xwc = min(xw, 29);
    int basex[2];
#pragma unroll
    for (int ry = 0; ry < 2; ++ry) {
        int ryg = mt * 2 + ry;
        int n = ryg / 30, y = ryg - n * 30;
        basex[ry] = n * CHW + y * W_IN + xwc;
    }
    const int kq4 = t >> 5, ks = kq4 * 4;
    const int ow64 = ot * 2 + (wave >> 1);
    const int idx0 = (wave * 2) & 3;
    const unsigned short* aP =
        wTf + ((size_t)ow64 * KITER * 4 + idx0) * 512 + (size_t)lane * 8;
    const unsigned short* bB[2] = {
        &Bs[0][lo * BSTR + quad * 8], &Bs[1][lo * BSTR + quad * 8] };
    unsigned short* bW[2] = {
        &Bs[0][xw * BSTR + ks], &Bs[1][xw * BSTR + ks] };
    __syncthreads();
    f32x4 acc[2][4] = {};
    bf16x8 aR[2][2];
    float v[2][2][4];
    {
        int4 k4 = *(const int4*)&koS[ks];
#pragma unroll
        for (int ry = 0; ry < 2; ++ry)
#pragma unroll
            for (int j = 0; j < 4; ++j)
                v[0][ry][j] = x[basex[ry] + ((const int*)&k4)[j]];
    }
    asm volatile("s_waitcnt vmcnt(0)" ::: "memory");
#pragma unroll
    for (int ry = 0; ry < 2; ++ry) {
        unsigned int u0 = (unsigned int)f2bf(v[0][ry][0]) |
                          ((unsigned int)f2bf(v[0][ry][1]) << 16);
        unsigned int u1 = (unsigned int)f2bf(v[0][ry][2]) |
                          ((unsigned int)f2bf(v[0][ry][3]) << 16);
        uint2 pk; pk.x = u0; pk.y = u1;
        *reinterpret_cast<uint2*>(bW[0] + ry * 32 * BSTR) = pk;
    }
#pragma unroll
    for (int ms = 0; ms < 2; ++ms)
        aR[0][ms] = *(const bf16x8*)(aP + (size_t)ms * 512);
    {
        int4 k4 = *(const int4*)&koS[32 + ks];
#pragma unroll
        for (int ry = 0; ry < 2; ++ry)
#pragma unroll
            for (int j = 0; j < 4; ++j)
                v[1][ry][j] = x[basex[ry] + ((const int*)&k4)[j]];
    }
    asm volatile("s_waitcnt lgkmcnt(0)" ::: "memory");
    __builtin_amdgcn_s_barrier();
#pragma unroll 2
    for (int kt = 0; kt < KITER; ++kt) {
        const int p = kt & 1, q = p ^ 1;
        bf16x8 b[4];
#pragma unroll
        for (int ns = 0; ns < 4; ++ns)
            b[ns] = *(const bf16x8*)(bB[p] + ns * 16 * BSTR);
        {
            const int k1 = (kt + 1 < KITER ? kt + 1 : KITER - 1);
#pragma unroll
            for (int ms = 0; ms < 2; ++ms)
                aR[q][ms] = *(const bf16x8*)(aP + (size_t)(k1 * 4 + ms) * 512);
        }
        {
            const int k2 = (kt + 2 < KITER ? kt + 2 : KITER - 1) * 32;
            int4 k4 = *(const int4*)&koS[k2 + ks];
#pragma unroll
            for (int ry = 0; ry < 2; ++ry)
#pragma unroll
                for (int j = 0; j < 4; ++j)
                    v[p][ry][j] = x[basex[ry] + ((const int*)&k4)[j]];
        }
        asm volatile("s_waitcnt vmcnt(10)" ::: "memory");
        asm volatile("s_waitcnt lgkmcnt(0)" ::: "memory");
        __builtin_amdgcn_sched_barrier(0);
#pragma unroll
        for (int ry = 0; ry < 2; ++ry) {
            unsigned int u0 = (unsigned int)f2bf(v[q][ry][0]) |
                              ((unsigned int)f2bf(v[q][ry][1]) << 16);
            unsigned int u1 = (unsigned int)f2bf(v[q][ry][2]) |
                              ((unsigned int)f2bf(v[q][ry][3]) << 16);
            uint2 pk; pk.x = u0; pk.y = u1;
            *reinterpret_cast<uint2*>(bW[q] + ry * 32 * BSTR) = pk;
        }
#pragma unroll
        for (int ms = 0; ms < 2; ++ms)
#pragma unroll
            for (int ns = 0; ns < 4; ++ns)
                acc[ms][ns] = __builtin_amdgcn_mfma_f32_16x16x32_bf16(
                    aR[p][ms], b[ns], acc[ms][ns], 0, 0, 0);
        asm volatile("s_waitcnt lgkmcnt(0)" ::: "memory");
        __builtin_amdgcn_s_barrier();
    }
#pragma unroll
    for (int ns = 0; ns < 4; ++ns) {
        const int mh  = mBase + ns * 16 + lo;
        const int xwe = mh & 31;
        const int ryg = mh >> 5;
        const int n = ryg / 30, y = ryg - n * 30;
        if (xwe < OW) {
            const size_t ob = (size_t)n * (OUTC * OUT_SP) + (size_t)y * OW + xwe;
#pragma unroll
            for (int ms = 0; ms < 2; ++ms) {
                const int o0 = oBase + wave * 32 + ms * 16 + quad * 4;
#pragma unroll
                for (int r = 0; r < 4; ++r)
                    out[ob + (size_t)(o0 + r) * OUT_SP] = acc[ms][ns][r];
            }
        }
    }
}

// ---------------------------------------------------------------------------
extern "C" void kernel_launch(void* const* d_in, const int* in_sizes, int n_in,
                              void* d_out, int out_size, void* d_ws, size_t ws_size,
                              hipStream_t stream) {
    const float* x   = (const float*)d_in[0];
    const float* w   = (const float*)d_in[1];
    const int*   idx = (const int*)d_in[2];
    float*       out = (float*)d_out;
    char* ws = (char*)d_ws;

    if (ws_size >= (size_t)WTF_BYTES + BF_BYTES) {
        // PATH A: ws = wTf 1.18MB | Bf 35.4MB (fragment-packed im2col)
        unsigned short* wTf = (unsigned short*)ws;
        unsigned short* Bf  = (unsigned short*)(ws + WTF_BYTES);
        prepA_kernel<<<dim3(NPACK + NPREPW), dim3(256), 0, stream>>>(
            idx, w, x, wTf, Bf);
        gemmA_kernel<<<dim3(NMT * NOT), dim3(256), 0, stream>>>(wTf, Bf, out);
    } else {
        // PATH B (R12 fallback): ws = koff 4608B | wTf 1.18MB
        int*            koff = (int*)ws;
        unsigned short* wTf  = (unsigned short*)(ws + 4608);
        prepB_kernel<<<dim3(K_SEL / 32, OUTC / 32), dim3(256), 0, stream>>>(
            idx, w, koff, wTf);
        gemmB_kernel<<<dim3(NMT * NOT), dim3(256), 0, stream>>>(wTf, x, koff, out);
    }
}